// Round 1
// baseline (308.354 us; speedup 1.0000x reference)
//
#include <hip/hip_runtime.h>
#include <hip/hip_bf16.h>

#define BH (512*2048)
#define LDT 40   // LDS row pitch in bf16 elems (32 + 8 pad -> conflict-balanced b128)

typedef __attribute__((ext_vector_type(8))) short short8;
typedef __attribute__((ext_vector_type(4))) float floatx4;
typedef __attribute__((ext_vector_type(4))) unsigned short ushort4v;
typedef __attribute__((ext_vector_type(8))) unsigned short ushort8v;

__device__ inline unsigned short f2bf(float x){
    unsigned u = __builtin_bit_cast(unsigned, x);
    return (unsigned short)((u + 0x7fffu + ((u >> 16) & 1u)) >> 16);
}

// GEMM over M=512, N=8192 (4 gates x 2048), K=4096 (2048 inputs + 2048 prevstate).
// Gates i,f,g pre-activation -> dout slots 0..2; gate c_ pre-activation -> ws.
__global__ __launch_bounds__(512, 1) void gemm_gates(
    const float* __restrict__ inputs, const float* __restrict__ states,
    const float* __restrict__ Wi, const float* __restrict__ Ui,
    const float* __restrict__ Wf, const float* __restrict__ Uf,
    const float* __restrict__ Wg, const float* __restrict__ Ug,
    const float* __restrict__ Wc, const float* __restrict__ Uc,
    float* __restrict__ dout, float* __restrict__ wsf)
{
    __shared__ unsigned short As[128 * LDT];
    __shared__ unsigned short Bs[128 * LDT];

    const int t    = threadIdx.x;
    const int m0   = blockIdx.y * 128;
    const int nblk = blockIdx.x;          // 0..63
    const int gate = nblk >> 4;           // 16 n-tiles per gate
    const int c0   = (nblk & 15) * 128;   // column within gate

    const float* Wp; const float* Up;
    switch (gate) {
        case 0:  Wp = Wi; Up = Ui; break;
        case 1:  Wp = Wf; Up = Uf; break;
        case 2:  Wp = Wg; Up = Ug; break;
        default: Wp = Wc; Up = Uc; break;
    }

    // 8 waves: 4 in m x 2 in n; wave tile 32x64
    const int lane  = t & 63;
    const int wave  = t >> 6;
    const int wm    = (wave & 3) * 32;
    const int wn    = (wave >> 2) * 64;
    const int row16 = lane & 15;
    const int oct   = lane >> 4;

    // A staging: thread -> (col4 = t&7, rows t>>3 and t>>3 + 64)
    const int a_c4 = t & 7;
    const int a_r0 = t >> 3;
    // B staging: thread -> (n = t&127, k-octet = t>>7)
    const int b_n   = t & 127;
    const int b_oct = t >> 7;

    floatx4 acc[2][4];
    #pragma unroll
    for (int i = 0; i < 2; i++)
        #pragma unroll
        for (int j = 0; j < 4; j++)
            acc[i][j] = (floatx4){0.f, 0.f, 0.f, 0.f};

    for (int kk = 0; kk < 128; kk++) {
        const int k0 = kk * 32;
        const float* aptr = (k0 < 2048)
            ? (inputs + (size_t)m0 * 2048 + k0)
            : (states + (size_t)m0 * 2048 + (k0 - 2048));   // states[0] = prevstate
        const float* bptr = (k0 < 2048)
            ? (Wp + (size_t)k0 * 2048 + c0)
            : (Up + (size_t)(k0 - 2048) * 2048 + c0);

        // global -> regs (fp32)
        floatx4 av0 = *(const floatx4*)(aptr + (size_t)a_r0 * 2048 + a_c4 * 4);
        floatx4 av1 = *(const floatx4*)(aptr + (size_t)(a_r0 + 64) * 2048 + a_c4 * 4);
        float bv[8];
        #pragma unroll
        for (int j = 0; j < 8; j++)
            bv[j] = bptr[(size_t)(b_oct * 8 + j) * 2048 + b_n];

        __syncthreads();   // previous iteration's fragment reads done

        // cvt + LDS writes (A: [m][k], B transposed: [n][k], both k-contiguous)
        ushort4v w0, w1;
        #pragma unroll
        for (int j = 0; j < 4; j++) { w0[j] = f2bf(av0[j]); w1[j] = f2bf(av1[j]); }
        *(ushort4v*)&As[a_r0 * LDT + a_c4 * 4]        = w0;
        *(ushort4v*)&As[(a_r0 + 64) * LDT + a_c4 * 4] = w1;
        ushort8v wb;
        #pragma unroll
        for (int j = 0; j < 8; j++) wb[j] = f2bf(bv[j]);
        *(ushort8v*)&Bs[b_n * LDT + b_oct * 8] = wb;

        __syncthreads();

        // fragments + MFMA
        short8 af[2], bfr[4];
        #pragma unroll
        for (int mi = 0; mi < 2; mi++)
            af[mi] = *(const short8*)&As[(wm + mi * 16 + row16) * LDT + oct * 8];
        #pragma unroll
        for (int ni = 0; ni < 4; ni++)
            bfr[ni] = *(const short8*)&Bs[(wn + ni * 16 + row16) * LDT + oct * 8];
        #pragma unroll
        for (int mi = 0; mi < 2; mi++)
            #pragma unroll
            for (int ni = 0; ni < 4; ni++)
                acc[mi][ni] = __builtin_amdgcn_mfma_f32_16x16x32_bf16(
                    af[mi], bfr[ni], acc[mi][ni], 0, 0, 0);
    }

    // epilogue: C/D layout col=lane&15, row=(lane>>4)*4+reg (m89-verified)
    float* dst = (gate < 3) ? (dout + (size_t)gate * BH) : wsf;
    #pragma unroll
    for (int mi = 0; mi < 2; mi++)
        #pragma unroll
        for (int ni = 0; ni < 4; ni++)
            #pragma unroll
            for (int j = 0; j < 4; j++) {
                int row = m0 + wm + mi * 16 + oct * 4 + j;
                int col = c0 + wn + ni * 16 + row16;
                dst[(size_t)row * 2048 + col] = acc[mi][ni][j];
            }
}

// elementwise: activations + LSTM combine, in-place on d_out
__global__ __launch_bounds__(256) void combine_kernel(
    float* __restrict__ out, const float* __restrict__ wsf,
    const float* __restrict__ states,
    const float* __restrict__ bi, const float* __restrict__ bfv,
    const float* __restrict__ bg, const float* __restrict__ bc)
{
    int idx = (blockIdx.x * 256 + threadIdx.x) * 4;
    int h = idx & 2047;
    const float* po = states + BH;   // states[1] = prevoutput

    floatx4 gi  = *(const floatx4*)&out[idx];
    floatx4 gf  = *(const floatx4*)&out[BH + idx];
    floatx4 gg  = *(const floatx4*)&out[2 * BH + idx];
    floatx4 gc  = *(const floatx4*)&wsf[idx];
    floatx4 pov = *(const floatx4*)&po[idx];

    floatx4 vc, vs;
    #pragma unroll
    for (int j = 0; j < 4; j++) {
        float xi = gi[j] + bi[h + j];
        float xf = gf[j] + bfv[h + j];
        float xg = gg[j] + bg[h + j];
        float xc = gc[j] + bc[h + j];
        float si = 1.f / (1.f + __expf(-xi));
        float sf = 1.f / (1.f + __expf(-xf));
        float sg = 1.f / (1.f + __expf(-xg));
        float tc = tanhf(xc);
        float c  = sf * pov[j] + si * tc;
        vc[j] = c;
        vs[j] = sg * tanhf(c);
    }
    *(floatx4*)&out[idx]          = vc;   // c
    *(floatx4*)&out[BH + idx]     = vs;   // state
    *(floatx4*)&out[2 * BH + idx] = vc;   // c
}

extern "C" void kernel_launch(void* const* d_in, const int* in_sizes, int n_in,
                              void* d_out, int out_size, void* d_ws, size_t ws_size,
                              hipStream_t stream) {
    const float* inputs = (const float*)d_in[0];
    const float* states = (const float*)d_in[1];
    const float* Wi = (const float*)d_in[2];
    const float* Ui = (const float*)d_in[3];
    const float* bi = (const float*)d_in[4];
    const float* Wf = (const float*)d_in[5];
    const float* Uf = (const float*)d_in[6];
    const float* bf = (const float*)d_in[7];
    const float* Wg = (const float*)d_in[8];
    const float* Ug = (const float*)d_in[9];
    const float* bg = (const float*)d_in[10];
    const float* Wc = (const float*)d_in[11];
    const float* Uc = (const float*)d_in[12];
    const float* bc = (const float*)d_in[13];
    float* out = (float*)d_out;
    float* wsf = (float*)d_ws;

    dim3 grid(64, 4);   // 64 n-tiles (4 gates x 16) x 4 m-tiles = 256 blocks
    gemm_gates<<<grid, 512, 0, stream>>>(inputs, states, Wi, Ui, Wf, Uf,
                                         Wg, Ug, Wc, Uc, out, wsf);
    combine_kernel<<<BH / (4 * 256), 256, 0, stream>>>(out, wsf, states, bi, bf, bg, bc);
}

// Round 2
// 241.602 us; speedup vs baseline: 1.2763x; 1.2763x over previous
//
#include <hip/hip_runtime.h>
#include <hip/hip_bf16.h>

#define BH (512*2048)
#define LDT 40   // LDS row pitch in bf16 elems (32 + 8 pad; rows stay 16B-aligned)
#define PPLANE (512ull*8192ull)   // one K-half partial: [512][8192] bf16

typedef __attribute__((ext_vector_type(8))) short short8;
typedef __attribute__((ext_vector_type(4))) float floatx4;
typedef __attribute__((ext_vector_type(4))) unsigned short ushort4v;
typedef __attribute__((ext_vector_type(8))) unsigned short ushort8v;

__device__ inline unsigned short f2bf(float x){
    unsigned u = __builtin_bit_cast(unsigned, x);
    return (unsigned short)((u + 0x7fffu + ((u >> 16) & 1u)) >> 16);
}
__device__ inline float bf2f(unsigned short s){
    unsigned u = ((unsigned)s) << 16;
    return __builtin_bit_cast(float, u);
}
__device__ inline float fsig(float x){
    // 1/(1+e^-x), division-free; x->-inf: rcp(inf)=0; x->+inf: rcp(1)=1
    return __builtin_amdgcn_rcpf(1.f + __expf(-x));
}
__device__ inline float ftanh(float x){
    return 2.f * fsig(2.f * x) - 1.f;   // NaN-free at both extremes
}

// One K-half of the gate GEMM. z=0: inputs @ W*, z=1: prevstate @ U*.
// Output: bf16 partial pre-activations P[z][row][gate*2048 + col].
__global__ __launch_bounds__(512, 1) void gemm_half(
    const float* __restrict__ inputs, const float* __restrict__ states,
    const float* __restrict__ Wi, const float* __restrict__ Ui,
    const float* __restrict__ Wf, const float* __restrict__ Uf,
    const float* __restrict__ Wg, const float* __restrict__ Ug,
    const float* __restrict__ Wc, const float* __restrict__ Uc,
    unsigned short* __restrict__ P)
{
    __shared__ unsigned short As[128 * LDT];
    __shared__ unsigned short Bs[128 * LDT];

    const int t    = threadIdx.x;
    const int m0   = blockIdx.y * 128;
    const int z    = blockIdx.z;          // K-half select
    const int nblk = blockIdx.x;          // 0..63
    const int gate = nblk >> 4;
    const int c0   = (nblk & 15) * 128;

    const float* Bsel;
    if (z == 0) {
        switch (gate) { case 0: Bsel = Wi; break; case 1: Bsel = Wf; break;
                        case 2: Bsel = Wg; break; default: Bsel = Wc; }
    } else {
        switch (gate) { case 0: Bsel = Ui; break; case 1: Bsel = Uf; break;
                        case 2: Bsel = Ug; break; default: Bsel = Uc; }
    }
    const float* Abase = (z == 0) ? inputs : states;   // states[0] = prevstate

    // 8 waves: 4 in m x 2 in n; wave tile 32x64
    const int lane  = t & 63;
    const int wave  = t >> 6;
    const int wm    = (wave & 3) * 32;
    const int wn    = (wave >> 2) * 64;
    const int row16 = lane & 15;
    const int oct   = lane >> 4;

    // A staging: thread -> (col4 = t&7, rows t>>3 and t>>3 + 64)
    const int a_c4 = t & 7;
    const int a_r0 = t >> 3;
    // B staging: thread -> (n = t&127, k-octet = t>>7)
    const int b_n   = t & 127;
    const int b_oct = t >> 7;

    floatx4 acc[2][4];
    #pragma unroll
    for (int i = 0; i < 2; i++)
        #pragma unroll
        for (int j = 0; j < 4; j++)
            acc[i][j] = (floatx4){0.f, 0.f, 0.f, 0.f};

    for (int kk = 0; kk < 64; kk++) {     // K-half = 2048
        const int k0 = kk * 32;
        const float* aptr = Abase + (size_t)m0 * 2048 + k0;
        const float* bptr = Bsel + (size_t)k0 * 2048 + c0;

        floatx4 av0 = *(const floatx4*)(aptr + (size_t)a_r0 * 2048 + a_c4 * 4);
        floatx4 av1 = *(const floatx4*)(aptr + (size_t)(a_r0 + 64) * 2048 + a_c4 * 4);
        float bv[8];
        #pragma unroll
        for (int j = 0; j < 8; j++)
            bv[j] = bptr[(size_t)(b_oct * 8 + j) * 2048 + b_n];

        __syncthreads();   // previous iteration's fragment reads done

        ushort4v w0, w1;
        #pragma unroll
        for (int j = 0; j < 4; j++) { w0[j] = f2bf(av0[j]); w1[j] = f2bf(av1[j]); }
        *(ushort4v*)&As[a_r0 * LDT + a_c4 * 4]        = w0;
        *(ushort4v*)&As[(a_r0 + 64) * LDT + a_c4 * 4] = w1;
        ushort8v wb;
        #pragma unroll
        for (int j = 0; j < 8; j++) wb[j] = f2bf(bv[j]);
        *(ushort8v*)&Bs[b_n * LDT + b_oct * 8] = wb;

        __syncthreads();

        short8 af[2], bfr[4];
        #pragma unroll
        for (int mi = 0; mi < 2; mi++)
            af[mi] = *(const short8*)&As[(wm + mi * 16 + row16) * LDT + oct * 8];
        #pragma unroll
        for (int ni = 0; ni < 4; ni++)
            bfr[ni] = *(const short8*)&Bs[(wn + ni * 16 + row16) * LDT + oct * 8];
        #pragma unroll
        for (int mi = 0; mi < 2; mi++)
            #pragma unroll
            for (int ni = 0; ni < 4; ni++)
                acc[mi][ni] = __builtin_amdgcn_mfma_f32_16x16x32_bf16(
                    af[mi], bfr[ni], acc[mi][ni], 0, 0, 0);
    }

    // epilogue: C/D layout col=lane&15, row=(lane>>4)*4+reg
    unsigned short* dst = P + (size_t)z * PPLANE;
    const int gbase = gate * 2048 + c0;
    #pragma unroll
    for (int mi = 0; mi < 2; mi++)
        #pragma unroll
        for (int ni = 0; ni < 4; ni++)
            #pragma unroll
            for (int j = 0; j < 4; j++) {
                int row = m0 + wm + mi * 16 + oct * 4 + j;
                int col = gbase + wn + ni * 16 + row16;
                dst[(size_t)row * 8192 + col] = f2bf(acc[mi][ni][j]);
            }
}

// activations + LSTM combine; reads bf16 partials, writes final fp32 outputs
__global__ __launch_bounds__(256) void combine_kernel(
    float* __restrict__ out, const unsigned short* __restrict__ P,
    const float* __restrict__ states,
    const float* __restrict__ bi, const float* __restrict__ bfv,
    const float* __restrict__ bg, const float* __restrict__ bc)
{
    const int idx = (blockIdx.x * 256 + threadIdx.x) * 8;   // 8 elems/thread
    const int row = idx >> 11;
    const int h   = idx & 2047;
    const size_t base = (size_t)row * 8192 + h;
    const unsigned short* P1 = P + PPLANE;
    const float* po = states + BH;   // states[1] = prevoutput

    ushort8v ai0 = *(const ushort8v*)&P [base];
    ushort8v ai1 = *(const ushort8v*)&P1[base];
    ushort8v af0 = *(const ushort8v*)&P [base + 2048];
    ushort8v af1 = *(const ushort8v*)&P1[base + 2048];
    ushort8v ag0 = *(const ushort8v*)&P [base + 4096];
    ushort8v ag1 = *(const ushort8v*)&P1[base + 4096];
    ushort8v ac0 = *(const ushort8v*)&P [base + 6144];
    ushort8v ac1 = *(const ushort8v*)&P1[base + 6144];

    floatx4 pov[2], vbi[2], vbf[2], vbg[2], vbc[2];
    #pragma unroll
    for (int q = 0; q < 2; q++) {
        pov[q] = *(const floatx4*)&po [idx + q * 4];
        vbi[q] = *(const floatx4*)&bi [h + q * 4];
        vbf[q] = *(const floatx4*)&bfv[h + q * 4];
        vbg[q] = *(const floatx4*)&bg [h + q * 4];
        vbc[q] = *(const floatx4*)&bc [h + q * 4];
    }

    floatx4 vc[2], vs[2];
    #pragma unroll
    for (int q = 0; q < 2; q++)
        #pragma unroll
        for (int j = 0; j < 4; j++) {
            int e = q * 4 + j;
            float xi = bf2f(ai0[e]) + bf2f(ai1[e]) + vbi[q][j];
            float xf = bf2f(af0[e]) + bf2f(af1[e]) + vbf[q][j];
            float xg = bf2f(ag0[e]) + bf2f(ag1[e]) + vbg[q][j];
            float xc = bf2f(ac0[e]) + bf2f(ac1[e]) + vbc[q][j];
            float c  = fsig(xf) * pov[q][j] + fsig(xi) * ftanh(xc);
            vc[q][j] = c;
            vs[q][j] = fsig(xg) * ftanh(c);
        }
    #pragma unroll
    for (int q = 0; q < 2; q++) {
        *(floatx4*)&out[idx + q * 4]          = vc[q];   // c
        *(floatx4*)&out[BH + idx + q * 4]     = vs[q];   // state
        *(floatx4*)&out[2 * BH + idx + q * 4] = vc[q];   // c
    }
}

extern "C" void kernel_launch(void* const* d_in, const int* in_sizes, int n_in,
                              void* d_out, int out_size, void* d_ws, size_t ws_size,
                              hipStream_t stream) {
    const float* inputs = (const float*)d_in[0];
    const float* states = (const float*)d_in[1];
    const float* Wi = (const float*)d_in[2];
    const float* Ui = (const float*)d_in[3];
    const float* bi = (const float*)d_in[4];
    const float* Wf = (const float*)d_in[5];
    const float* Uf = (const float*)d_in[6];
    const float* bf = (const float*)d_in[7];
    const float* Wg = (const float*)d_in[8];
    const float* Ug = (const float*)d_in[9];
    const float* bg = (const float*)d_in[10];
    const float* Wc = (const float*)d_in[11];
    const float* Uc = (const float*)d_in[12];
    const float* bc = (const float*)d_in[13];
    float* out = (float*)d_out;
    unsigned short* P = (unsigned short*)d_ws;   // 2 x [512][8192] bf16 = 16.8 MB

    dim3 grid(64, 4, 2);   // 64 n-tiles x 4 m-tiles x 2 K-halves = 512 blocks
    gemm_half<<<grid, 512, 0, stream>>>(inputs, states, Wi, Ui, Wf, Uf,
                                        Wg, Ug, Wc, Uc, P);
    combine_kernel<<<BH / (8 * 256), 256, 0, stream>>>(out, P, states, bi, bf, bg, bc);
}

// Round 3
// 238.108 us; speedup vs baseline: 1.2950x; 1.0147x over previous
//
#include <hip/hip_runtime.h>

#define BH (512*2048)
#define PPLANE (512ull*8192ull)          // elems per partial plane [512][8192]
#define PLANE_BYTES (PPLANE*2ull)        // bf16

typedef __attribute__((ext_vector_type(8))) short short8;
typedef __attribute__((ext_vector_type(4))) float floatx4;
typedef __attribute__((ext_vector_type(4))) unsigned int uint4v;
typedef __attribute__((ext_vector_type(8))) unsigned short ushort8v;

// pack two f32 -> two bf16 (round-half-up) in one dword: 3 VALU ops
__device__ inline unsigned pk2(float a, float b){
    unsigned ua = __builtin_bit_cast(unsigned, a) + 0x8000u;
    unsigned ub = __builtin_bit_cast(unsigned, b) + 0x8000u;
    return __builtin_amdgcn_perm(ub, ua, 0x07060302u);   // [ub.hi16 | ua.hi16]
}
__device__ inline unsigned short f2bf1(float x){
    return (unsigned short)((__builtin_bit_cast(unsigned, x) + 0x8000u) >> 16);
}
__device__ inline float bf2f(unsigned short s){
    return __builtin_bit_cast(float, ((unsigned)s) << 16);
}
// 16B-granule XOR swizzle: tile row r (0..127), k-octet g (0..3).
// Spreads every staging-write and fragment-read pattern evenly over 8 bank-groups.
__device__ inline int swz(int r, int g){ return r*4 + (g ^ ((r>>1)&3)); }

__device__ inline float fsig(float x){ return __builtin_amdgcn_rcpf(1.f + __expf(-x)); }
__device__ inline float ftanh(float x){ return 2.f*fsig(2.f*x) - 1.f; }

// One K-slice of the gate GEMM. Block tile 128x128, 4 waves of 64x64 (4x4 MFMA
// 16x16x32), BK=32, double-buffered LDS, single barrier per K-iter.
__global__ __launch_bounds__(256, 2) void gemm_tile(
    const float* __restrict__ inputs, const float* __restrict__ states,
    const float* __restrict__ Wi, const float* __restrict__ Ui,
    const float* __restrict__ Wf, const float* __restrict__ Uf,
    const float* __restrict__ Wg, const float* __restrict__ Ug,
    const float* __restrict__ Wc, const float* __restrict__ Uc,
    unsigned short* __restrict__ P, int KB)
{
    __shared__ uint4v As[2][512];   // 128 rows x 4 k-octet granules, swizzled
    __shared__ uint4v Bs[2][512];

    const int t    = threadIdx.x;
    const int m0   = blockIdx.y * 128;
    const int z    = blockIdx.z;
    const int nblk = blockIdx.x;
    const int gate = nblk >> 4;
    const int c0   = (nblk & 15) * 128;
    const int gk   = z * KB;

    const float* Abase; const float* Bsel; int ko;
    if (gk < 2048) {
        Abase = inputs; ko = gk;
        switch (gate){ case 0: Bsel=Wi; break; case 1: Bsel=Wf; break;
                       case 2: Bsel=Wg; break; default: Bsel=Wc; }
    } else {
        Abase = states; ko = gk - 2048;     // states[0] = prevstate
        switch (gate){ case 0: Bsel=Ui; break; case 1: Bsel=Uf; break;
                       case 2: Bsel=Ug; break; default: Bsel=Uc; }
    }
    const int NIT = KB >> 5;

    const int lane  = t & 63;
    const int wave  = t >> 6;
    const int wm    = (wave & 1) * 64;
    const int wn    = (wave >> 1) * 64;
    const int row16 = lane & 15;
    const int g4    = lane >> 4;            // k-octet of fragment

    // staging assignments
    const int ar  = t >> 2;                 // A rows ar, ar+64; k-octet ag
    const int ag  = t & 3;
    const int bn  = t & 127;                // B col bn; k-octets bg2, bg2+1
    const int bg2 = (t >> 7) * 2;

    const float* Ap = Abase + (size_t)(m0 + ar) * 2048 + ko + ag * 8;
    const float* Bp = Bsel  + (size_t)ko * 2048 + c0 + bn;

    floatx4 acc[4][4];
    #pragma unroll
    for (int i = 0; i < 4; i++)
        #pragma unroll
        for (int j = 0; j < 4; j++)
            acc[i][j] = (floatx4){0.f,0.f,0.f,0.f};

    floatx4 a0,a1,a2,a3;
    float b0[8], b1[8];

    // prologue: load + write buffer 0
    a0 = *(const floatx4*)Ap;            a1 = *(const floatx4*)(Ap + 4);
    a2 = *(const floatx4*)(Ap + 64*2048); a3 = *(const floatx4*)(Ap + 64*2048 + 4);
    #pragma unroll
    for (int j = 0; j < 8; j++) b0[j] = Bp[(size_t)(bg2*8 + j) * 2048];
    #pragma unroll
    for (int j = 0; j < 8; j++) b1[j] = Bp[(size_t)(bg2*8 + 8 + j) * 2048];
    {
        uint4v w;
        w.x=pk2(a0[0],a0[1]); w.y=pk2(a0[2],a0[3]); w.z=pk2(a1[0],a1[1]); w.w=pk2(a1[2],a1[3]);
        As[0][swz(ar, ag)] = w;
        w.x=pk2(a2[0],a2[1]); w.y=pk2(a2[2],a2[3]); w.z=pk2(a3[0],a3[1]); w.w=pk2(a3[2],a3[3]);
        As[0][swz(ar+64, ag)] = w;
        w.x=pk2(b0[0],b0[1]); w.y=pk2(b0[2],b0[3]); w.z=pk2(b0[4],b0[5]); w.w=pk2(b0[6],b0[7]);
        Bs[0][swz(bn, bg2)] = w;
        w.x=pk2(b1[0],b1[1]); w.y=pk2(b1[2],b1[3]); w.z=pk2(b1[4],b1[5]); w.w=pk2(b1[6],b1[7]);
        Bs[0][swz(bn, bg2+1)] = w;
    }

    for (int kk = 0; kk < NIT; kk++) {
        __syncthreads();                 // buffer (kk&1) ready for all waves
        const int cur = kk & 1;

        if (kk + 1 < NIT) {              // prefetch next tile into registers
            const float* ap = Ap + (kk+1) * 32;
            a0 = *(const floatx4*)ap;             a1 = *(const floatx4*)(ap + 4);
            a2 = *(const floatx4*)(ap + 64*2048); a3 = *(const floatx4*)(ap + 64*2048 + 4);
            const float* bp = Bp + (size_t)(kk+1) * 32 * 2048;
            #pragma unroll
            for (int j = 0; j < 8; j++) b0[j] = bp[(size_t)(bg2*8 + j) * 2048];
            #pragma unroll
            for (int j = 0; j < 8; j++) b1[j] = bp[(size_t)(bg2*8 + 8 + j) * 2048];
        }

        short8 afr[4], bfr[4];
        #pragma unroll
        for (int mi = 0; mi < 4; mi++)
            afr[mi] = *(const short8*)&As[cur][swz(wm + mi*16 + row16, g4)];
        #pragma unroll
        for (int ni = 0; ni < 4; ni++)
            bfr[ni] = *(const short8*)&Bs[cur][swz(wn + ni*16 + row16, g4)];
        #pragma unroll
        for (int mi = 0; mi < 4; mi++)
            #pragma unroll
            for (int ni = 0; ni < 4; ni++)
                acc[mi][ni] = __builtin_amdgcn_mfma_f32_16x16x32_bf16(
                    afr[mi], bfr[ni], acc[mi][ni], 0, 0, 0);

        if (kk + 1 < NIT) {              // cvt + write the other buffer
            const int nxt = cur ^ 1;
            uint4v w;
            w.x=pk2(a0[0],a0[1]); w.y=pk2(a0[2],a0[3]); w.z=pk2(a1[0],a1[1]); w.w=pk2(a1[2],a1[3]);
            As[nxt][swz(ar, ag)] = w;
            w.x=pk2(a2[0],a2[1]); w.y=pk2(a2[2],a2[3]); w.z=pk2(a3[0],a3[1]); w.w=pk2(a3[2],a3[3]);
            As[nxt][swz(ar+64, ag)] = w;
            w.x=pk2(b0[0],b0[1]); w.y=pk2(b0[2],b0[3]); w.z=pk2(b0[4],b0[5]); w.w=pk2(b0[6],b0[7]);
            Bs[nxt][swz(bn, bg2)] = w;
            w.x=pk2(b1[0],b1[1]); w.y=pk2(b1[2],b1[3]); w.z=pk2(b1[4],b1[5]); w.w=pk2(b1[6],b1[7]);
            Bs[nxt][swz(bn, bg2+1)] = w;
        }
    }

    // epilogue: C/D layout col=lane&15, row=(lane>>4)*4+reg (m89-verified)
    unsigned short* dst = P + (size_t)z * PPLANE;
    const int gbase = gate * 2048 + c0;
    #pragma unroll
    for (int mi = 0; mi < 4; mi++)
        #pragma unroll
        for (int ni = 0; ni < 4; ni++)
            #pragma unroll
            for (int j = 0; j < 4; j++) {
                int row = m0 + wm + mi*16 + g4*4 + j;
                int col = gbase + wn + ni*16 + row16;
                dst[(size_t)row * 8192 + col] = f2bf1(acc[mi][ni][j]);
            }
}

// activations + LSTM combine; sums nz bf16 partial planes, writes fp32 outputs
__global__ __launch_bounds__(256) void combine_kernel(
    float* __restrict__ out, const unsigned short* __restrict__ P,
    const float* __restrict__ states,
    const float* __restrict__ bi, const float* __restrict__ bfv,
    const float* __restrict__ bg, const float* __restrict__ bc, int nz)
{
    const int idx = (blockIdx.x * 256 + threadIdx.x) * 8;
    const int row = idx >> 11;
    const int h   = idx & 2047;
    const size_t base = (size_t)row * 8192 + h;

    float xi[8], xf[8], xg[8], xc[8];
    #pragma unroll
    for (int e = 0; e < 8; e++) {
        xi[e] = bi[h+e]; xf[e] = bfv[h+e]; xg[e] = bg[h+e]; xc[e] = bc[h+e];
    }
    for (int z = 0; z < nz; z++) {
        const unsigned short* Pz = P + (size_t)z * PPLANE;
        ushort8v vi = *(const ushort8v*)&Pz[base];
        ushort8v vf = *(const ushort8v*)&Pz[base + 2048];
        ushort8v vg = *(const ushort8v*)&Pz[base + 4096];
        ushort8v vc = *(const ushort8v*)&Pz[base + 6144];
        #pragma unroll
        for (int e = 0; e < 8; e++) {
            xi[e] += bf2f(vi[e]); xf[e] += bf2f(vf[e]);
            xg[e] += bf2f(vg[e]); xc[e] += bf2f(vc[e]);
        }
    }

    const float* po = states + BH;       // states[1] = prevoutput
    floatx4 pov[2];
    pov[0] = *(const floatx4*)&po[idx];
    pov[1] = *(const floatx4*)&po[idx + 4];

    floatx4 vcv[2], vsv[2];
    #pragma unroll
    for (int q = 0; q < 2; q++)
        #pragma unroll
        for (int j = 0; j < 4; j++) {
            int e = q*4 + j;
            float c = fsig(xf[e]) * pov[q][j] + fsig(xi[e]) * ftanh(xc[e]);
            vcv[q][j] = c;
            vsv[q][j] = fsig(xg[e]) * ftanh(c);
        }
    #pragma unroll
    for (int q = 0; q < 2; q++) {
        *(floatx4*)&out[idx + q*4]          = vcv[q];   // c
        *(floatx4*)&out[BH + idx + q*4]     = vsv[q];   // state
        *(floatx4*)&out[2*BH + idx + q*4]   = vcv[q];   // c
    }
}

extern "C" void kernel_launch(void* const* d_in, const int* in_sizes, int n_in,
                              void* d_out, int out_size, void* d_ws, size_t ws_size,
                              hipStream_t stream) {
    const float* inputs = (const float*)d_in[0];
    const float* states = (const float*)d_in[1];
    const float* Wi = (const float*)d_in[2];
    const float* Ui = (const float*)d_in[3];
    const float* bi = (const float*)d_in[4];
    const float* Wf = (const float*)d_in[5];
    const float* Uf = (const float*)d_in[6];
    const float* bf = (const float*)d_in[7];
    const float* Wg = (const float*)d_in[8];
    const float* Ug = (const float*)d_in[9];
    const float* bg = (const float*)d_in[10];
    const float* Wc = (const float*)d_in[11];
    const float* Uc = (const float*)d_in[12];
    const float* bc = (const float*)d_in[13];
    float* out = (float*)d_out;
    unsigned short* P = (unsigned short*)d_ws;

    // 4-way K-split (4 blocks/CU) if scratch allows 4 partial planes, else 2-way
    const int nz = (ws_size >= 4 * PLANE_BYTES) ? 4 : 2;
    const int KB = 4096 / nz;

    dim3 grid(64, 4, nz);
    gemm_tile<<<grid, 256, 0, stream>>>(inputs, states, Wi, Ui, Wf, Uf,
                                        Wg, Ug, Wc, Uc, P, KB);
    combine_kernel<<<BH / (8 * 256), 256, 0, stream>>>(out, P, states,
                                                       bi, bf, bg, bc, nz);
}